// Round 3
// baseline (304.070 us; speedup 1.0000x reference)
//
#include <hip/hip_runtime.h>

#define RPB 256  // rows per block == threads per block

typedef float fx4 __attribute__((ext_vector_type(4)));
typedef float fx2 __attribute__((ext_vector_type(2)));

__global__ __launch_bounds__(RPB) void se3_ham_kernel(
    const float* __restrict__ in, float* __restrict__ out, int n_rows) {
    __shared__ float s[RPB * 22];

    const int block_row = blockIdx.x * RPB;
    int count = n_rows - block_row;
    if (count > RPB) count = RPB;
    if (count <= 0) return;
    const int nf  = count * 22;
    const int nf4 = nf >> 2;

    // ---- cooperative vectorized load: global -> LDS ----
    const float* gin  = in + (size_t)block_row * 22;
    const fx4*   gin4 = (const fx4*)gin;
    fx4* s4 = (fx4*)s;
    for (int i = threadIdx.x; i < nf4; i += RPB) s4[i] = gin4[i];
    for (int i = (nf4 << 2) + threadIdx.x; i < nf; i += RPB) s[i] = gin[i];
    __syncthreads();

    // ---- per-row physics (diagonal mass/inertia -> all elementwise) ----
    // Thread t reads AND writes only row t: no cross-thread hazard, so no
    // barrier is needed between the read and the in-place write-back.
    const int t = threadIdx.x;
    if (t < count) {
        fx2* row2 = (fx2*)&s[t * 22];  // t*88 B is 8B-aligned
        fx2 tmp[11];
        #pragma unroll
        for (int j = 0; j < 11; ++j) tmp[j] = row2[j];  // ds_read_b64 x11
        float r[22];
        #pragma unroll
        for (int j = 0; j < 11; ++j) { r[2*j] = tmp[j].x; r[2*j+1] = tmp[j].y; }

        const float R00=r[3],  R01=r[4],  R02=r[5];
        const float R10=r[6],  R11=r[7],  R12=r[8];
        const float R20=r[9],  R21=r[10], R22=r[11];
        const float qv0=r[12], qv1=r[13], qv2=r[14];
        const float qw0=r[15], qw1=r[16], qw2=r[17];
        const float u0 =r[18], u1 =r[19], u2 =r[20], u3=r[21];

        const float M1d   = (float)(1.0 / (1.0 / 0.027));   // inv(M*I) diag
        const float Minv  = (float)(1.0 / 0.027);           // M1_INV diag
        const float Jx    = (float)2.3951e-05;
        const float Jz    = (float)3.2347e-05;
        const float Jxinv = (float)(1.0 / 2.3951e-05);
        const float Jzinv = (float)(1.0 / 3.2347e-05);
        const float MG    = (float)(0.027 * 9.81);

        // momenta
        const float pv0 = M1d * qv0, pv1 = M1d * qv1, pv2 = M1d * qv2;
        const float pw0 = Jx * qw0,  pw1 = Jx * qw1,  pw2 = Jz * qw2;
        // gradients
        const float hv0 = Minv * pv0, hv1 = Minv * pv1, hv2 = Minv * pv2;
        const float hw0 = Jxinv * pw0, hw1 = Jxinv * pw1, hw2 = Jzinv * pw2;

        float o[22];
        // dx = R * dHdpv
        o[0] = R00*hv0 + R01*hv1 + R02*hv2;
        o[1] = R10*hv0 + R11*hv1 + R12*hv2;
        o[2] = R20*hv0 + R21*hv1 + R22*hv2;
        // dR rows: cross(R_row_i, hw)
        o[3]  = R01*hw2 - R02*hw1;  o[4]  = R02*hw0 - R00*hw2;  o[5]  = R00*hw1 - R01*hw0;
        o[6]  = R11*hw2 - R12*hw1;  o[7]  = R12*hw0 - R10*hw2;  o[8]  = R10*hw1 - R11*hw0;
        o[9]  = R21*hw2 - R22*hw1;  o[10] = R22*hw0 - R20*hw2;  o[11] = R20*hw1 - R21*hw0;
        // dpv = cross(pv, hw) - MG*R_row2 + (0,0,u0)
        const float dpv0 = (pv1*hw2 - pv2*hw1) - MG*R20;
        const float dpv1 = (pv2*hw0 - pv0*hw2) - MG*R21;
        const float dpv2 = (pv0*hw1 - pv1*hw0) - MG*R22 + u0;
        // dpw = cross(pw, hw) + cross(pv, hv) + (u1,u2,u3)
        const float dpw0 = (pw1*hw2 - pw2*hw1) + (pv1*hv2 - pv2*hv1) + u1;
        const float dpw1 = (pw2*hw0 - pw0*hw2) + (pv2*hv0 - pv0*hv2) + u2;
        const float dpw2 = (pw0*hw1 - pw1*hw0) + (pv0*hv1 - pv1*hv0) + u3;
        // dv = Minv * dpv ; dw = Jinv * dpw
        o[12] = Minv * dpv0;  o[13] = Minv * dpv1;  o[14] = Minv * dpv2;
        o[15] = Jxinv * dpw0; o[16] = Jxinv * dpw1; o[17] = Jzinv * dpw2;
        o[18] = 0.0f; o[19] = 0.0f; o[20] = 0.0f; o[21] = 0.0f;

        // in-place write-back, ds_write_b64 x11
        #pragma unroll
        for (int j = 0; j < 11; ++j) {
            fx2 w; w.x = o[2*j]; w.y = o[2*j+1];
            row2[j] = w;
        }
    }
    __syncthreads();

    // ---- cooperative vectorized store: LDS -> global (nontemporal) ----
    float* gout  = out + (size_t)block_row * 22;
    fx4*   gout4 = (fx4*)gout;
    for (int i = threadIdx.x; i < nf4; i += RPB)
        __builtin_nontemporal_store(s4[i], &gout4[i]);
    for (int i = (nf4 << 2) + threadIdx.x; i < nf; i += RPB)
        __builtin_nontemporal_store(s[i], &gout[i]);
}

extern "C" void kernel_launch(void* const* d_in, const int* in_sizes, int n_in,
                              void* d_out, int out_size, void* d_ws, size_t ws_size,
                              hipStream_t stream) {
    // d_in[0] = t (unused scalar), d_in[1] = input [BS, 22] float32
    const float* x = (const float*)d_in[1];
    float* y = (float*)d_out;
    const int n_rows = in_sizes[1] / 22;
    const int blocks = (n_rows + RPB - 1) / RPB;
    se3_ham_kernel<<<blocks, RPB, 0, stream>>>(x, y, n_rows);
}

// Round 4
// 303.129 us; speedup vs baseline: 1.0031x; 1.0031x over previous
//
#include <hip/hip_runtime.h>

#define TPB 256
#define RPW 64            // rows per wave (one row per lane)
#define WPB 4             // waves per block

typedef float fx4 __attribute__((ext_vector_type(4)));
typedef float fx2 __attribute__((ext_vector_type(2)));

// Wave-autonomous: each wave owns a private LDS slice and processes 64 rows
// end-to-end with NO __syncthreads. Cross-lane exchange happens only within
// the wave through its slice; compiler-inserted s_waitcnt lgkmcnt orders the
// ds_write -> ds_read dependency (lockstep wave => visible to all lanes).
__global__ __launch_bounds__(TPB) void se3_ham_kernel(
    const float* __restrict__ in, float* __restrict__ out, int n_rows) {
    __shared__ float s[WPB][RPW * 22];

    const int wave = threadIdx.x >> 6;
    const int lane = threadIdx.x & 63;
    const int chunk = blockIdx.x * WPB + wave;
    const int row0 = chunk * RPW;
    if (row0 >= n_rows) return;
    int cnt = n_rows - row0;
    if (cnt > RPW) cnt = RPW;
    const int nf  = cnt * 22;
    const int nf4 = nf >> 2;

    float* sw = s[wave];
    fx4*   sw4 = (fx4*)sw;

    // ---- wave-cooperative vectorized load: global -> LDS slice ----
    const float* gin  = in + (size_t)row0 * 22;
    const fx4*   gin4 = (const fx4*)gin;
    for (int i = lane; i < nf4; i += 64) sw4[i] = gin4[i];
    for (int i = (nf4 << 2) + lane; i < nf; i += 64) sw[i] = gin[i];

    // ---- per-row physics (lane t owns row t of this wave's slice) ----
    if (lane < cnt) {
        fx2* row2 = (fx2*)&sw[lane * 22];  // lane*88 B, 8B-aligned
        fx2 tmp[11];
        #pragma unroll
        for (int j = 0; j < 11; ++j) tmp[j] = row2[j];
        float r[22];
        #pragma unroll
        for (int j = 0; j < 11; ++j) { r[2*j] = tmp[j].x; r[2*j+1] = tmp[j].y; }

        const float R00=r[3],  R01=r[4],  R02=r[5];
        const float R10=r[6],  R11=r[7],  R12=r[8];
        const float R20=r[9],  R21=r[10], R22=r[11];
        const float qv0=r[12], qv1=r[13], qv2=r[14];
        const float qw0=r[15], qw1=r[16], qw2=r[17];
        const float u0 =r[18], u1 =r[19], u2 =r[20], u3=r[21];

        const float M1d   = (float)(1.0 / (1.0 / 0.027));   // inv(M*I) diag
        const float Minv  = (float)(1.0 / 0.027);           // M1_INV diag
        const float Jx    = (float)2.3951e-05;
        const float Jz    = (float)3.2347e-05;
        const float Jxinv = (float)(1.0 / 2.3951e-05);
        const float Jzinv = (float)(1.0 / 3.2347e-05);
        const float MG    = (float)(0.027 * 9.81);

        // momenta
        const float pv0 = M1d * qv0, pv1 = M1d * qv1, pv2 = M1d * qv2;
        const float pw0 = Jx * qw0,  pw1 = Jx * qw1,  pw2 = Jz * qw2;
        // gradients
        const float hv0 = Minv * pv0, hv1 = Minv * pv1, hv2 = Minv * pv2;
        const float hw0 = Jxinv * pw0, hw1 = Jxinv * pw1, hw2 = Jzinv * pw2;

        float o[22];
        // dx = R * dHdpv
        o[0] = R00*hv0 + R01*hv1 + R02*hv2;
        o[1] = R10*hv0 + R11*hv1 + R12*hv2;
        o[2] = R20*hv0 + R21*hv1 + R22*hv2;
        // dR rows: cross(R_row_i, hw)
        o[3]  = R01*hw2 - R02*hw1;  o[4]  = R02*hw0 - R00*hw2;  o[5]  = R00*hw1 - R01*hw0;
        o[6]  = R11*hw2 - R12*hw1;  o[7]  = R12*hw0 - R10*hw2;  o[8]  = R10*hw1 - R11*hw0;
        o[9]  = R21*hw2 - R22*hw1;  o[10] = R22*hw0 - R20*hw2;  o[11] = R20*hw1 - R21*hw0;
        // dpv = cross(pv, hw) - MG*R_row2 + (0,0,u0)
        const float dpv0 = (pv1*hw2 - pv2*hw1) - MG*R20;
        const float dpv1 = (pv2*hw0 - pv0*hw2) - MG*R21;
        const float dpv2 = (pv0*hw1 - pv1*hw0) - MG*R22 + u0;
        // dpw = cross(pw, hw) + cross(pv, hv) + (u1,u2,u3)
        const float dpw0 = (pw1*hw2 - pw2*hw1) + (pv1*hv2 - pv2*hv1) + u1;
        const float dpw1 = (pw2*hw0 - pw0*hw2) + (pv2*hv0 - pv0*hv2) + u2;
        const float dpw2 = (pw0*hw1 - pw1*hw0) + (pv0*hv1 - pv1*hv0) + u3;
        // dv = Minv * dpv ; dw = Jinv * dpw
        o[12] = Minv * dpv0;  o[13] = Minv * dpv1;  o[14] = Minv * dpv2;
        o[15] = Jxinv * dpw0; o[16] = Jxinv * dpw1; o[17] = Jzinv * dpw2;
        o[18] = 0.0f; o[19] = 0.0f; o[20] = 0.0f; o[21] = 0.0f;

        #pragma unroll
        for (int j = 0; j < 11; ++j) {
            fx2 w; w.x = o[2*j]; w.y = o[2*j+1];
            row2[j] = w;
        }
    }

    // ---- wave-cooperative vectorized store: LDS slice -> global (NT) ----
    float* gout  = out + (size_t)row0 * 22;
    fx4*   gout4 = (fx4*)gout;
    for (int i = lane; i < nf4; i += 64)
        __builtin_nontemporal_store(sw4[i], &gout4[i]);
    for (int i = (nf4 << 2) + lane; i < nf; i += 64)
        __builtin_nontemporal_store(sw[i], &gout[i]);
}

extern "C" void kernel_launch(void* const* d_in, const int* in_sizes, int n_in,
                              void* d_out, int out_size, void* d_ws, size_t ws_size,
                              hipStream_t stream) {
    // d_in[0] = t (unused scalar), d_in[1] = input [BS, 22] float32
    const float* x = (const float*)d_in[1];
    float* y = (float*)d_out;
    const int n_rows = in_sizes[1] / 22;
    const int chunks = (n_rows + RPW - 1) / RPW;
    const int blocks = (chunks + WPB - 1) / WPB;
    se3_ham_kernel<<<blocks, TPB, 0, stream>>>(x, y, n_rows);
}